// Round 6
// baseline (538.425 us; speedup 1.0000x reference)
//
#include <hip/hip_runtime.h>
#include <hip/hip_bf16.h>
#include <math.h>

// EncoderBlock: B=2, S=4096, D_MODEL=768, H=12, dk=64, D_FF=3072.
// Inputs fp32 (mask int32), output fp32. Internal compute bf16 MFMA.
// Round 6: attn 64q/block (grid 1536 = 6/CU), __expf softmax (exp2f was the
// round-5 VALU regression), Q pre-scaled by exact 0.125; fused prep kernel.

typedef __hip_bfloat16 bf16;
typedef short short8 __attribute__((ext_vector_type(8)));   // 8 bf16 (4 VGPRs)
typedef short short4v __attribute__((ext_vector_type(4)));  // 4 bf16 (8B)
typedef float f32x4 __attribute__((ext_vector_type(4)));

#define MFMA(A, B, C) __builtin_amdgcn_mfma_f32_16x16x32_bf16(A, B, C, 0, 0, 0)

__device__ __forceinline__ void gl_lds16(const void* g, void* l) {
  __builtin_amdgcn_global_load_lds(
      (__attribute__((address_space(1))) void*)g,
      (__attribute__((address_space(3))) void*)l, 16, 0, 0);
}

__device__ __forceinline__ short f2b(float f) {
  bf16 h = __float2bfloat16(f);
  return *reinterpret_cast<short*>(&h);
}

// ---------------- fused prep: all weight fp32->bf16 + biases + mask bias -----
__global__ __launch_bounds__(256)
void prep_all(const float* __restrict__ wq, const float* __restrict__ wk,
              const float* __restrict__ wv, const float* __restrict__ wo,
              const float* __restrict__ w1, const float* __restrict__ w2,
              const float* __restrict__ bq, const float* __restrict__ bk,
              const float* __restrict__ bv, const int* __restrict__ mask,
              bf16* __restrict__ wqkvb, bf16* __restrict__ wob,
              bf16* __restrict__ w1b, bf16* __restrict__ w2b,
              float* __restrict__ bqkv, float* __restrict__ bias_g)
{
  const int i = blockIdx.x * 256 + threadIdx.x;   // float4 index, exact grid
  const int W = 147456;   // 768*768/4
  const int F = 589824;   // 3072*768/4
  const float* src; bf16* dst; int off;
  if (i < W)          { src = wq; dst = wqkvb;           off = i; }
  else if (i < 2*W)   { src = wk; dst = wqkvb + 589824;  off = i - W; }
  else if (i < 3*W)   { src = wv; dst = wqkvb + 1179648; off = i - 2*W; }
  else if (i < 4*W)   { src = wo; dst = wob;             off = i - 3*W; }
  else if (i < 4*W+F) { src = w1; dst = w1b;             off = i - 4*W; }
  else                { src = w2; dst = w2b;             off = i - 4*W - F; }
  float4 v = ((const float4*)src)[off];
  short4v o;
  o.x = f2b(v.x); o.y = f2b(v.y); o.z = f2b(v.z); o.w = f2b(v.w);
  ((short4v*)dst)[off] = o;
  if (i < 2304)
    bqkv[i] = (i < 768) ? bq[i] : (i < 1536 ? bk[i - 768] : bv[i - 1536]);
  if (i < 8192)
    bias_g[i] = mask[i] ? 0.f : -1e9f;
}

// ---------------- LayerNorm (scalar alpha/beta, unbiased std) ----------------
template<typename INT>
__global__ __launch_bounds__(256)
void ln_kernel(const INT* __restrict__ x, bf16* __restrict__ out,
               const float* __restrict__ alpha, const float* __restrict__ beta)
{
  const int row = blockIdx.x;
  const long base = (long)row * 768;
  const int t = threadIdx.x;
  float v[3]; float s = 0.f, ss = 0.f;
#pragma unroll
  for (int i = 0; i < 3; i++) {
    v[i] = (float)x[base + t + i * 256];
    s += v[i]; ss += v[i] * v[i];
  }
#pragma unroll
  for (int off = 32; off > 0; off >>= 1) {
    s  += __shfl_down(s, off);
    ss += __shfl_down(ss, off);
  }
  __shared__ float red[8];
  __shared__ float stats[2];
  const int w = t >> 6;
  if ((t & 63) == 0) { red[w] = s; red[4 + w] = ss; }
  __syncthreads();
  if (t == 0) {
    float S  = red[0] + red[1] + red[2] + red[3];
    float SS = red[4] + red[5] + red[6] + red[7];
    float mean = S * (1.f / 768.f);
    float var = fmaxf((SS - 768.f * mean * mean) * (1.f / 767.f), 0.f);
    stats[0] = mean;
    stats[1] = 1.f / (sqrtf(var) + 1e-6f);   // 1/(std+eps)
  }
  __syncthreads();
  const float mean = stats[0], rinv = stats[1];
  const float a = alpha[0], b = beta[0];
#pragma unroll
  for (int i = 0; i < 3; i++)
    out[base + t + i * 256] = __float2bfloat16(a * (v[i] - mean) * rinv + b);
}

// ---------------- generic GEMM: C = A*W^T + bias ------------------------------
// MODE: 1 +ReLU | 4 +residual R[m][n]
template<int MODE, typename RT, typename OUTT>
__global__ __launch_bounds__(256)
void gemm_bt(const bf16* __restrict__ A, const bf16* __restrict__ W,
             const float* __restrict__ bias, const RT* __restrict__ R,
             OUTT* __restrict__ Cout, int M, int N, int K)
{
  __shared__ __align__(16) bf16 sA[128 * 32];
  __shared__ __align__(16) bf16 sB[128 * 32];
  const int t = threadIdx.x;
  const int w = t >> 6, lane = t & 63;
  const int lr = lane & 15, quad = lane >> 4;
  const int tm = blockIdx.x * 128, tn = blockIdx.y * 128;
  const int wm = (w >> 1) * 64, wn = (w & 1) * 64;

  const int srow = w * 16 + (lane >> 2);
  const int scol = (lane & 3) * 8;
  const bf16* Ap = A + (long)(tm + srow) * K + scol;
  const bf16* Wp = W + (long)(tn + srow) * K + scol;
  bf16* sAp = &sA[srow * 32 + scol];
  bf16* sBp = &sB[srow * 32 + scol];
  const long half = (long)64 * K;

  f32x4 acc[4][4] = {};

  for (int kb = 0; kb < K; kb += 32) {
    gl_lds16(Ap + kb, sAp);
    gl_lds16(Ap + kb + half, sAp + 64 * 32);
    gl_lds16(Wp + kb, sBp);
    gl_lds16(Wp + kb + half, sBp + 64 * 32);
    __syncthreads();
    short8 af[4], bfr[4];
#pragma unroll
    for (int i = 0; i < 4; i++)
      af[i] = *(const short8*)&sA[(wm + i * 16 + lr) * 32 + quad * 8];
#pragma unroll
    for (int j = 0; j < 4; j++)
      bfr[j] = *(const short8*)&sB[(wn + j * 16 + lr) * 32 + quad * 8];
#pragma unroll
    for (int i = 0; i < 4; i++)
#pragma unroll
      for (int j = 0; j < 4; j++)
        acc[i][j] = MFMA(af[i], bfr[j], acc[i][j]);
    __syncthreads();
  }

#pragma unroll
  for (int i = 0; i < 4; i++) {
#pragma unroll
    for (int j = 0; j < 4; j++) {
      const int col = tn + wn + j * 16 + lr;
      const float bv = bias[col];
#pragma unroll
      for (int r = 0; r < 4; r++) {
        const int m = tm + wm + i * 16 + quad * 4 + r;
        float vv = acc[i][j][r] + bv;
        if (MODE == 1) vv = fmaxf(vv, 0.f);
        if (MODE == 4) vv += (float)R[(long)m * N + col];
        Cout[(long)m * N + col] = (OUTT)vv;
      }
    }
  }
}

// ---------------- fused QKV GEMM: N=2304, region-scatter epilogue -----------
// cols [0,768): Q scaled by 0.125 (exact) -> [B,H,S,64]; [768,1536): K;
// [1536,2304): V -> [B,H,64,S] (transposed). Region is block-uniform.
__global__ __launch_bounds__(256)
void gemm_qkv(const bf16* __restrict__ A, const bf16* __restrict__ W,
              const float* __restrict__ bias,
              bf16* __restrict__ Qo, bf16* __restrict__ Ko, bf16* __restrict__ Vt)
{
  const int K = 768;
  __shared__ __align__(16) bf16 sA[128 * 32];
  __shared__ __align__(16) bf16 sB[128 * 32];
  const int t = threadIdx.x;
  const int w = t >> 6, lane = t & 63;
  const int lr = lane & 15, quad = lane >> 4;
  const int tm = blockIdx.x * 128, tn = blockIdx.y * 128;
  const int wm = (w >> 1) * 64, wn = (w & 1) * 64;

  const int srow = w * 16 + (lane >> 2);
  const int scol = (lane & 3) * 8;
  const bf16* Ap = A + (long)(tm + srow) * K + scol;
  const bf16* Wp = W + (long)(tn + srow) * K + scol;
  bf16* sAp = &sA[srow * 32 + scol];
  bf16* sBp = &sB[srow * 32 + scol];
  const long half = (long)64 * K;

  f32x4 acc[4][4] = {};

  for (int kb = 0; kb < K; kb += 32) {
    gl_lds16(Ap + kb, sAp);
    gl_lds16(Ap + kb + half, sAp + 64 * 32);
    gl_lds16(Wp + kb, sBp);
    gl_lds16(Wp + kb + half, sBp + 64 * 32);
    __syncthreads();
    short8 af[4], bfr[4];
#pragma unroll
    for (int i = 0; i < 4; i++)
      af[i] = *(const short8*)&sA[(wm + i * 16 + lr) * 32 + quad * 8];
#pragma unroll
    for (int j = 0; j < 4; j++)
      bfr[j] = *(const short8*)&sB[(wn + j * 16 + lr) * 32 + quad * 8];
#pragma unroll
    for (int i = 0; i < 4; i++)
#pragma unroll
      for (int j = 0; j < 4; j++)
        acc[i][j] = MFMA(af[i], bfr[j], acc[i][j]);
    __syncthreads();
  }

  const int region = (tn >= 1536) ? 2 : (tn >= 768 ? 1 : 0);  // block-uniform
#pragma unroll
  for (int i = 0; i < 4; i++) {
#pragma unroll
    for (int j = 0; j < 4; j++) {
      const int col = tn + wn + j * 16 + lr;
      const int c768 = col - region * 768;
      const int hh = c768 >> 6, d = c768 & 63;
      const float bv = bias[col];
#pragma unroll
      for (int r = 0; r < 4; r++) {
        const int m = tm + wm + i * 16 + quad * 4 + r;
        const int bb = m >> 12, sdx = m & 4095;
        float vv = acc[i][j][r] + bv;
        if (region == 0) {
          vv *= 0.125f;   // exact pow2: folds 1/sqrt(dk) into Q, no extra rounding
          Qo[((long)(bb * 12 + hh) * 4096 + sdx) * 64 + d] = __float2bfloat16(vv);
        } else if (region == 1) {
          Ko[((long)(bb * 12 + hh) * 4096 + sdx) * 64 + d] = __float2bfloat16(vv);
        } else {
          Vt[((long)(bb * 12 + hh) * 64 + d) * 4096 + sdx] = __float2bfloat16(vv);
        }
      }
    }
  }
}

// ---------------- Flash attention (bounded-score softmax, no running max) ----
// Q (pre-scaled 0.125), K: [B,H,S,64]; Vt: [B,H,64,S]; ctx: [B,S,768].
// Block: 4 waves x 16 q = 64 q; chunk 64 keys; grid (64, 24) = 1536 blocks.
// LDS 27648 B -> 5 blocks/CU. Mask bias via global fp32 (L1-cached).
__global__ __launch_bounds__(256)
void attn_kernel(const bf16* __restrict__ Q, const bf16* __restrict__ Kg,
                 const bf16* __restrict__ Vt, const float* __restrict__ bias_g,
                 bf16* __restrict__ ctx)
{
  __shared__ __align__(16) bf16 sK[64 * 72];      // [key][d], stride 72
  __shared__ __align__(16) bf16 sV[64 * 72];      // [d][key], stride 72
  __shared__ __align__(16) bf16 sP[4][16 * 72];   // per-wave P [q][key]

  const int t = threadIdx.x, w = t >> 6, lane = t & 63;
  const int lr = lane & 15, quad = lane >> 4;
  const int bh = blockIdx.y, b = bh / 12, hh = bh % 12;
  const int qb = blockIdx.x * 64 + w * 16;        // this wave's 16 queries
  const long bh_s = (long)bh * 4096;
  const float* bg = bias_g + b * 4096;

  // Q fragments (A-layout): lane holds Q[qb+lr][quad*8+j], two d-halves
  const bf16* qp = Q + (bh_s + qb + lr) * 64 + quad * 8;
  short8 q0 = *(const short8*)qp;
  short8 q1 = *(const short8*)(qp + 32);

  float l_part[4] = {};
  f32x4 O[4] = {};

  // staging: thread t owns key-rows {t>>3, 32+(t>>3)} x 8 d-cols (V: d-rows)
  const int srow = t >> 3;          // 0..31
  const int scol = (t & 7) * 8;     // 0..56
  const bf16* kp0 = Kg + (bh_s + srow) * 64 + scol;
  const bf16* kp1 = Kg + (bh_s + srow + 32) * 64 + scol;
  const bf16* vp0 = Vt + ((long)bh * 64 + srow) * 4096 + scol;
  const bf16* vp1 = Vt + ((long)bh * 64 + srow + 32) * 4096 + scol;

  for (int kc = 0; kc < 4096; kc += 64) {
    short8 k0 = *(const short8*)(kp0 + (long)kc * 64);
    short8 k1 = *(const short8*)(kp1 + (long)kc * 64);
    short8 v0 = *(const short8*)(vp0 + kc);
    short8 v1 = *(const short8*)(vp1 + kc);
    float bb[4];
#pragma unroll
    for (int kt = 0; kt < 4; kt++) bb[kt] = bg[kc + kt * 16 + lr];
    __syncthreads();   // previous chunk's LDS reads complete
    *(short8*)&sK[srow * 72 + scol]        = k0;
    *(short8*)&sK[(srow + 32) * 72 + scol] = k1;
    *(short8*)&sV[srow * 72 + scol]        = v0;
    *(short8*)&sV[(srow + 32) * 72 + scol] = v1;
    __syncthreads();   // staged data visible

    // ---- S = Q' K^T : 4 ktiles x 2 d-halves = 8 MFMA ----
    f32x4 s[4] = {};
#pragma unroll
    for (int kt = 0; kt < 4; kt++) {
      short8 kfa = *(const short8*)&sK[(kt * 16 + lr) * 72 + quad * 8];
      short8 kfb = *(const short8*)&sK[(kt * 16 + lr) * 72 + 32 + quad * 8];
      s[kt] = MFMA(q0, kfa, s[kt]);
      s[kt] = MFMA(q1, kfb, s[kt]);
    }

    // ---- p = exp(s + bias); accumulate l; P -> wave-private LDS ----
#pragma unroll
    for (int kt = 0; kt < 4; kt++) {
#pragma unroll
      for (int r = 0; r < 4; r++) {
        const float p = __expf(s[kt][r] + bb[kt]);
        l_part[r] += p;
        sP[w][(quad * 4 + r) * 72 + kt * 16 + lr] = __float2bfloat16(p);
      }
    }
    // wave-private sP: lgkmcnt ordering only, no barrier needed

    // ---- O += P V : 4 d-blocks x 2 k-halves = 8 MFMA ----
    short8 pf0 = *(const short8*)&sP[w][lr * 72 + quad * 8];
    short8 pf1 = *(const short8*)&sP[w][lr * 72 + 32 + quad * 8];
#pragma unroll
    for (int j = 0; j < 4; j++) {
      short8 vfa = *(const short8*)&sV[(j * 16 + lr) * 72 + quad * 8];
      short8 vfb = *(const short8*)&sV[(j * 16 + lr) * 72 + 32 + quad * 8];
      O[j] = MFMA(pf0, vfa, O[j]);
      O[j] = MFMA(pf1, vfb, O[j]);
    }
  }

  // epilogue: reduce l over the 16 lr-lanes, normalize, store
#pragma unroll
  for (int r = 0; r < 4; r++) {
    float l = l_part[r];
#pragma unroll
    for (int off = 1; off < 16; off <<= 1) l += __shfl_xor(l, off, 16);
    const float il = (l > 0.f) ? 1.f / l : 0.f;
    const int q = qb + quad * 4 + r;
    bf16* cp = ctx + ((long)(b * 4096 + q)) * 768 + hh * 64 + lr;
#pragma unroll
    for (int j = 0; j < 4; j++)
      cp[j * 16] = __float2bfloat16(O[j][r] * il);
  }
}

// ---------------------------------------------------------------------------
extern "C" void kernel_launch(void* const* d_in, const int* in_sizes, int n_in,
                              void* d_out, int out_size, void* d_ws, size_t ws_size,
                              hipStream_t stream)
{
  (void)in_sizes; (void)n_in; (void)out_size; (void)ws_size;
  const float* x    = (const float*)d_in[0];
  const int*   mask = (const int*)  d_in[1];
  const float* wq = (const float*)d_in[2];  const float* bq = (const float*)d_in[3];
  const float* wk = (const float*)d_in[4];  const float* bk = (const float*)d_in[5];
  const float* wv = (const float*)d_in[6];  const float* bv = (const float*)d_in[7];
  const float* wo = (const float*)d_in[8];  const float* bo = (const float*)d_in[9];
  const float* w1 = (const float*)d_in[10]; const float* b1 = (const float*)d_in[11];
  const float* w2 = (const float*)d_in[12]; const float* b2 = (const float*)d_in[13];
  const float* alpha1 = (const float*)d_in[14]; const float* beta1 = (const float*)d_in[15];
  const float* alpha2 = (const float*)d_in[16]; const float* beta2 = (const float*)d_in[17];
  float* out = (float*)d_out;

  // ---- workspace layout (bytes) ----
  const long WSZ = (long)768 * 768 * 2;        // 1,179,648
  const long W1SZ = (long)3072 * 768 * 2;      // 4,718,592
  const long SZB = (long)8192 * 768 * 2;       // 12,582,912
  char* ws = (char*)d_ws;
  bf16* wqkvb = (bf16*)(ws);                   // wq|wk|wv contiguous [2304,768]
  bf16* wob = (bf16*)(ws + 3 * WSZ);
  bf16* w1b = (bf16*)(ws + 4 * WSZ);
  bf16* w2b = (bf16*)(ws + 4 * WSZ + W1SZ);
  float* bqkv   = (float*)(ws + 4 * WSZ + 2 * W1SZ);             // 2304 f32
  float* bias_g = (float*)(ws + 4 * WSZ + 2 * W1SZ + 9216);      // 8192 f32
  const long BASE = 16l << 20;
  bf16* h   = (bf16*)(ws + BASE);            // LN output (reused as h2)
  bf16* qws = (bf16*)(ws + BASE + 1 * SZB);  // Q [B,H,S,64] (pre-scaled 1/8)
  bf16* kws = (bf16*)(ws + BASE + 2 * SZB);  // K [B,H,S,64]
  bf16* vtw = (bf16*)(ws + BASE + 3 * SZB);  // V^T [B,H,64,S]
  bf16* ctx = (bf16*)(ws + BASE + 4 * SZB);  // attention context [B,S,768]
  bf16* x1  = (bf16*)(ws + BASE + 5 * SZB);  // residual-1 output (bf16)
  bf16* ff  = qws;                           // FFN hidden [8192,3072]

  dim3 blk(256);

  hipLaunchKernelGGL(prep_all, dim3(6912), blk, 0, stream,
                     wq, wk, wv, wo, w1, w2, bq, bk, bv, mask,
                     wqkvb, wob, w1b, w2b, bqkv, bias_g);

  hipLaunchKernelGGL((ln_kernel<float>), dim3(8192), blk, 0, stream, x, h, alpha1, beta1);
  hipLaunchKernelGGL(gemm_qkv, dim3(64, 18), blk, 0, stream, h, wqkvb, bqkv, qws, kws, vtw);
  hipLaunchKernelGGL(attn_kernel, dim3(64, 24), blk, 0, stream, qws, kws, vtw, bias_g, ctx);
  hipLaunchKernelGGL((gemm_bt<4, float, bf16>), dim3(64, 6), blk, 0, stream, ctx, wob, bo, x, x1, 8192, 768, 768);
  hipLaunchKernelGGL((ln_kernel<bf16>), dim3(8192), blk, 0, stream, x1, h, alpha2, beta2);
  hipLaunchKernelGGL((gemm_bt<1, float, bf16>), dim3(64, 24), blk, 0, stream, h, w1b, b1, (const float*)nullptr, ff, 8192, 3072, 768);
  hipLaunchKernelGGL((gemm_bt<4, bf16, float>), dim3(64, 6), blk, 0, stream, ff, w2b, b2, x1, out, 8192, 768, 3072);
}

// Round 7
// 493.635 us; speedup vs baseline: 1.0907x; 1.0907x over previous
//
#include <hip/hip_runtime.h>
#include <hip/hip_bf16.h>
#include <math.h>

// EncoderBlock: B=2, S=4096, D_MODEL=768, H=12, dk=64, D_FF=3072.
// Inputs fp32 (mask int32), output fp32. Internal compute bf16 MFMA.
// Round 7: attn reverted to round-4 structure (32q/wave — measured best),
// with global mask-bias + Q pre-scaled 0.125. Fused QKV GEMM + prep kept.

typedef __hip_bfloat16 bf16;
typedef short short8 __attribute__((ext_vector_type(8)));   // 8 bf16 (4 VGPRs)
typedef short short4v __attribute__((ext_vector_type(4)));  // 4 bf16 (8B)
typedef float f32x4 __attribute__((ext_vector_type(4)));

#define MFMA(A, B, C) __builtin_amdgcn_mfma_f32_16x16x32_bf16(A, B, C, 0, 0, 0)

__device__ __forceinline__ void gl_lds16(const void* g, void* l) {
  __builtin_amdgcn_global_load_lds(
      (__attribute__((address_space(1))) void*)g,
      (__attribute__((address_space(3))) void*)l, 16, 0, 0);
}

__device__ __forceinline__ short f2b(float f) {
  bf16 h = __float2bfloat16(f);
  return *reinterpret_cast<short*>(&h);
}

// ---------------- fused prep: all weight fp32->bf16 + biases + mask bias -----
__global__ __launch_bounds__(256)
void prep_all(const float* __restrict__ wq, const float* __restrict__ wk,
              const float* __restrict__ wv, const float* __restrict__ wo,
              const float* __restrict__ w1, const float* __restrict__ w2,
              const float* __restrict__ bq, const float* __restrict__ bk,
              const float* __restrict__ bv, const int* __restrict__ mask,
              bf16* __restrict__ wqkvb, bf16* __restrict__ wob,
              bf16* __restrict__ w1b, bf16* __restrict__ w2b,
              float* __restrict__ bqkv, float* __restrict__ bias_g)
{
  const int i = blockIdx.x * 256 + threadIdx.x;   // float4 index, exact grid
  const int W = 147456;   // 768*768/4
  const int F = 589824;   // 3072*768/4
  const float* src; bf16* dst; int off;
  if (i < W)          { src = wq; dst = wqkvb;           off = i; }
  else if (i < 2*W)   { src = wk; dst = wqkvb + 589824;  off = i - W; }
  else if (i < 3*W)   { src = wv; dst = wqkvb + 1179648; off = i - 2*W; }
  else if (i < 4*W)   { src = wo; dst = wob;             off = i - 3*W; }
  else if (i < 4*W+F) { src = w1; dst = w1b;             off = i - 4*W; }
  else                { src = w2; dst = w2b;             off = i - 4*W - F; }
  float4 v = ((const float4*)src)[off];
  short4v o;
  o.x = f2b(v.x); o.y = f2b(v.y); o.z = f2b(v.z); o.w = f2b(v.w);
  ((short4v*)dst)[off] = o;
  if (i < 2304)
    bqkv[i] = (i < 768) ? bq[i] : (i < 1536 ? bk[i - 768] : bv[i - 1536]);
  if (i < 8192)
    bias_g[i] = mask[i] ? 0.f : -1e9f;
}

// ---------------- LayerNorm (scalar alpha/beta, unbiased std) ----------------
template<typename INT>
__global__ __launch_bounds__(256)
void ln_kernel(const INT* __restrict__ x, bf16* __restrict__ out,
               const float* __restrict__ alpha, const float* __restrict__ beta)
{
  const int row = blockIdx.x;
  const long base = (long)row * 768;
  const int t = threadIdx.x;
  float v[3]; float s = 0.f, ss = 0.f;
#pragma unroll
  for (int i = 0; i < 3; i++) {
    v[i] = (float)x[base + t + i * 256];
    s += v[i]; ss += v[i] * v[i];
  }
#pragma unroll
  for (int off = 32; off > 0; off >>= 1) {
    s  += __shfl_down(s, off);
    ss += __shfl_down(ss, off);
  }
  __shared__ float red[8];
  __shared__ float stats[2];
  const int w = t >> 6;
  if ((t & 63) == 0) { red[w] = s; red[4 + w] = ss; }
  __syncthreads();
  if (t == 0) {
    float S  = red[0] + red[1] + red[2] + red[3];
    float SS = red[4] + red[5] + red[6] + red[7];
    float mean = S * (1.f / 768.f);
    float var = fmaxf((SS - 768.f * mean * mean) * (1.f / 767.f), 0.f);
    stats[0] = mean;
    stats[1] = 1.f / (sqrtf(var) + 1e-6f);   // 1/(std+eps)
  }
  __syncthreads();
  const float mean = stats[0], rinv = stats[1];
  const float a = alpha[0], b = beta[0];
#pragma unroll
  for (int i = 0; i < 3; i++)
    out[base + t + i * 256] = __float2bfloat16(a * (v[i] - mean) * rinv + b);
}

// ---------------- generic GEMM: C = A*W^T + bias ------------------------------
// MODE: 1 +ReLU | 4 +residual R[m][n]
template<int MODE, typename RT, typename OUTT>
__global__ __launch_bounds__(256)
void gemm_bt(const bf16* __restrict__ A, const bf16* __restrict__ W,
             const float* __restrict__ bias, const RT* __restrict__ R,
             OUTT* __restrict__ Cout, int M, int N, int K)
{
  __shared__ __align__(16) bf16 sA[128 * 32];
  __shared__ __align__(16) bf16 sB[128 * 32];
  const int t = threadIdx.x;
  const int w = t >> 6, lane = t & 63;
  const int lr = lane & 15, quad = lane >> 4;
  const int tm = blockIdx.x * 128, tn = blockIdx.y * 128;
  const int wm = (w >> 1) * 64, wn = (w & 1) * 64;

  const int srow = w * 16 + (lane >> 2);
  const int scol = (lane & 3) * 8;
  const bf16* Ap = A + (long)(tm + srow) * K + scol;
  const bf16* Wp = W + (long)(tn + srow) * K + scol;
  bf16* sAp = &sA[srow * 32 + scol];
  bf16* sBp = &sB[srow * 32 + scol];
  const long half = (long)64 * K;

  f32x4 acc[4][4] = {};

  for (int kb = 0; kb < K; kb += 32) {
    gl_lds16(Ap + kb, sAp);
    gl_lds16(Ap + kb + half, sAp + 64 * 32);
    gl_lds16(Wp + kb, sBp);
    gl_lds16(Wp + kb + half, sBp + 64 * 32);
    __syncthreads();
    short8 af[4], bfr[4];
#pragma unroll
    for (int i = 0; i < 4; i++)
      af[i] = *(const short8*)&sA[(wm + i * 16 + lr) * 32 + quad * 8];
#pragma unroll
    for (int j = 0; j < 4; j++)
      bfr[j] = *(const short8*)&sB[(wn + j * 16 + lr) * 32 + quad * 8];
#pragma unroll
    for (int i = 0; i < 4; i++)
#pragma unroll
      for (int j = 0; j < 4; j++)
        acc[i][j] = MFMA(af[i], bfr[j], acc[i][j]);
    __syncthreads();
  }

#pragma unroll
  for (int i = 0; i < 4; i++) {
#pragma unroll
    for (int j = 0; j < 4; j++) {
      const int col = tn + wn + j * 16 + lr;
      const float bv = bias[col];
#pragma unroll
      for (int r = 0; r < 4; r++) {
        const int m = tm + wm + i * 16 + quad * 4 + r;
        float vv = acc[i][j][r] + bv;
        if (MODE == 1) vv = fmaxf(vv, 0.f);
        if (MODE == 4) vv += (float)R[(long)m * N + col];
        Cout[(long)m * N + col] = (OUTT)vv;
      }
    }
  }
}

// ---------------- fused QKV GEMM: N=2304, region-scatter epilogue -----------
// cols [0,768): Q scaled by 0.125 (exact) -> [B,H,S,64]; [768,1536): K;
// [1536,2304): V -> [B,H,64,S] (transposed). Region is block-uniform.
__global__ __launch_bounds__(256)
void gemm_qkv(const bf16* __restrict__ A, const bf16* __restrict__ W,
              const float* __restrict__ bias,
              bf16* __restrict__ Qo, bf16* __restrict__ Ko, bf16* __restrict__ Vt)
{
  const int K = 768;
  __shared__ __align__(16) bf16 sA[128 * 32];
  __shared__ __align__(16) bf16 sB[128 * 32];
  const int t = threadIdx.x;
  const int w = t >> 6, lane = t & 63;
  const int lr = lane & 15, quad = lane >> 4;
  const int tm = blockIdx.x * 128, tn = blockIdx.y * 128;
  const int wm = (w >> 1) * 64, wn = (w & 1) * 64;

  const int srow = w * 16 + (lane >> 2);
  const int scol = (lane & 3) * 8;
  const bf16* Ap = A + (long)(tm + srow) * K + scol;
  const bf16* Wp = W + (long)(tn + srow) * K + scol;
  bf16* sAp = &sA[srow * 32 + scol];
  bf16* sBp = &sB[srow * 32 + scol];
  const long half = (long)64 * K;

  f32x4 acc[4][4] = {};

  for (int kb = 0; kb < K; kb += 32) {
    gl_lds16(Ap + kb, sAp);
    gl_lds16(Ap + kb + half, sAp + 64 * 32);
    gl_lds16(Wp + kb, sBp);
    gl_lds16(Wp + kb + half, sBp + 64 * 32);
    __syncthreads();
    short8 af[4], bfr[4];
#pragma unroll
    for (int i = 0; i < 4; i++)
      af[i] = *(const short8*)&sA[(wm + i * 16 + lr) * 32 + quad * 8];
#pragma unroll
    for (int j = 0; j < 4; j++)
      bfr[j] = *(const short8*)&sB[(wn + j * 16 + lr) * 32 + quad * 8];
#pragma unroll
    for (int i = 0; i < 4; i++)
#pragma unroll
      for (int j = 0; j < 4; j++)
        acc[i][j] = MFMA(af[i], bfr[j], acc[i][j]);
    __syncthreads();
  }

  const int region = (tn >= 1536) ? 2 : (tn >= 768 ? 1 : 0);  // block-uniform
#pragma unroll
  for (int i = 0; i < 4; i++) {
#pragma unroll
    for (int j = 0; j < 4; j++) {
      const int col = tn + wn + j * 16 + lr;
      const int c768 = col - region * 768;
      const int hh = c768 >> 6, d = c768 & 63;
      const float bv = bias[col];
#pragma unroll
      for (int r = 0; r < 4; r++) {
        const int m = tm + wm + i * 16 + quad * 4 + r;
        const int bb = m >> 12, sdx = m & 4095;
        float vv = acc[i][j][r] + bv;
        if (region == 0) {
          vv *= 0.125f;   // exact pow2: folds 1/sqrt(dk) into Q
          Qo[((long)(bb * 12 + hh) * 4096 + sdx) * 64 + d] = __float2bfloat16(vv);
        } else if (region == 1) {
          Ko[((long)(bb * 12 + hh) * 4096 + sdx) * 64 + d] = __float2bfloat16(vv);
        } else {
          Vt[((long)(bb * 12 + hh) * 64 + d) * 4096 + sdx] = __float2bfloat16(vv);
        }
      }
    }
  }
}

// ---------------- Flash attention (bounded-score softmax, no running max) ----
// Round-4 structure: 4 waves x 32 q = 128 q/block; chunk 64 keys; grid (32,24).
// Q (pre-scaled 0.125), K: [B,H,S,64]; Vt: [B,H,64,S]; ctx: [B,S,768].
// LDS 36864 B. Mask bias via global fp32 (L1-cached). __expf only.
__global__ __launch_bounds__(256)
void attn_kernel(const bf16* __restrict__ Q, const bf16* __restrict__ Kg,
                 const bf16* __restrict__ Vt, const float* __restrict__ bias_g,
                 bf16* __restrict__ ctx)
{
  __shared__ __align__(16) bf16 sK[64 * 72];      // [key][d], stride 72
  __shared__ __align__(16) bf16 sV[64 * 72];      // [d][key], stride 72
  __shared__ __align__(16) bf16 sP[4][32 * 72];   // per-wave P [q][key]

  const int t = threadIdx.x, w = t >> 6, lane = t & 63;
  const int lr = lane & 15, quad = lane >> 4;
  const int bh = blockIdx.y, b = bh / 12, hh = bh % 12;
  const int qb = blockIdx.x * 128 + w * 32;       // this wave's 32 queries
  const long bh_s = (long)bh * 4096;
  const float* bg = bias_g + b * 4096;

  // Q fragments (A-layout): lane holds Q[q=16qt+lr][d=quad*8+j], halves d<32/d>=32
  short8 qf[2][2];
#pragma unroll
  for (int qt = 0; qt < 2; qt++) {
    const bf16* qp = Q + (bh_s + qb + qt * 16 + lr) * 64 + quad * 8;
    qf[qt][0] = *(const short8*)qp;
    qf[qt][1] = *(const short8*)(qp + 32);
  }

  float l_part[2][4] = {};
  f32x4 O[2][4] = {};

  // staging: thread t owns key-rows {t>>3, 32+(t>>3)} x 8 d-cols (V: d-rows)
  const int srow = t >> 3;          // 0..31
  const int scol = (t & 7) * 8;     // 0..56
  const bf16* kp0 = Kg + (bh_s + srow) * 64 + scol;
  const bf16* kp1 = Kg + (bh_s + srow + 32) * 64 + scol;
  const bf16* vp0 = Vt + ((long)bh * 64 + srow) * 4096 + scol;
  const bf16* vp1 = Vt + ((long)bh * 64 + srow + 32) * 4096 + scol;

  for (int kc = 0; kc < 4096; kc += 64) {
    short8 k0 = *(const short8*)(kp0 + (long)kc * 64);
    short8 k1 = *(const short8*)(kp1 + (long)kc * 64);
    short8 v0 = *(const short8*)(vp0 + kc);
    short8 v1 = *(const short8*)(vp1 + kc);
    float bb[4];
#pragma unroll
    for (int kt = 0; kt < 4; kt++) bb[kt] = bg[kc + kt * 16 + lr];
    __syncthreads();   // previous chunk's LDS reads complete
    *(short8*)&sK[srow * 72 + scol]        = k0;
    *(short8*)&sK[(srow + 32) * 72 + scol] = k1;
    *(short8*)&sV[srow * 72 + scol]        = v0;
    *(short8*)&sV[(srow + 32) * 72 + scol] = v1;
    __syncthreads();   // staged data visible

    // ---- S = Q' K^T : 2 qtiles x 4 ktiles x 2 d-halves = 16 MFMA ----
    f32x4 s[2][4] = {};
#pragma unroll
    for (int kt = 0; kt < 4; kt++) {
      short8 kfa = *(const short8*)&sK[(kt * 16 + lr) * 72 + quad * 8];
      short8 kfb = *(const short8*)&sK[(kt * 16 + lr) * 72 + 32 + quad * 8];
      s[0][kt] = MFMA(qf[0][0], kfa, s[0][kt]);
      s[0][kt] = MFMA(qf[0][1], kfb, s[0][kt]);
      s[1][kt] = MFMA(qf[1][0], kfa, s[1][kt]);
      s[1][kt] = MFMA(qf[1][1], kfb, s[1][kt]);
    }

    // ---- p = exp(s + bias); accumulate l; P -> wave-private LDS ----
#pragma unroll
    for (int kt = 0; kt < 4; kt++) {
#pragma unroll
      for (int qt = 0; qt < 2; qt++) {
#pragma unroll
        for (int r = 0; r < 4; r++) {
          const float p = __expf(s[qt][kt][r] + bb[kt]);
          l_part[qt][r] += p;
          sP[w][(qt * 16 + quad * 4 + r) * 72 + kt * 16 + lr] = __float2bfloat16(p);
        }
      }
    }
    // wave-private sP: lgkmcnt ordering only, no barrier needed

    // ---- O += P V : 2 qtiles x 4 d-blocks x 2 k-halves = 16 MFMA ----
    short8 pf[2][2];
#pragma unroll
    for (int qt = 0; qt < 2; qt++) {
      pf[qt][0] = *(const short8*)&sP[w][(qt * 16 + lr) * 72 + quad * 8];
      pf[qt][1] = *(const short8*)&sP[w][(qt * 16 + lr) * 72 + 32 + quad * 8];
    }
#pragma unroll
    for (int j = 0; j < 4; j++) {
      short8 vfa = *(const short8*)&sV[(j * 16 + lr) * 72 + quad * 8];
      short8 vfb = *(const short8*)&sV[(j * 16 + lr) * 72 + 32 + quad * 8];
      O[0][j] = MFMA(pf[0][0], vfa, O[0][j]);
      O[0][j] = MFMA(pf[0][1], vfb, O[0][j]);
      O[1][j] = MFMA(pf[1][0], vfa, O[1][j]);
      O[1][j] = MFMA(pf[1][1], vfb, O[1][j]);
    }
  }

  // epilogue: reduce l over the 16 lr-lanes, normalize, store
#pragma unroll
  for (int qt = 0; qt < 2; qt++) {
#pragma unroll
    for (int r = 0; r < 4; r++) {
      float l = l_part[qt][r];
#pragma unroll
      for (int off = 1; off < 16; off <<= 1) l += __shfl_xor(l, off, 16);
      const float il = (l > 0.f) ? 1.f / l : 0.f;
      const int q = qb + qt * 16 + quad * 4 + r;
      bf16* cp = ctx + ((long)(b * 4096 + q)) * 768 + hh * 64 + lr;
#pragma unroll
      for (int j = 0; j < 4; j++)
        cp[j * 16] = __float2bfloat16(O[qt][j][r] * il);
    }
  }
}

// ---------------------------------------------------------------------------
extern "C" void kernel_launch(void* const* d_in, const int* in_sizes, int n_in,
                              void* d_out, int out_size, void* d_ws, size_t ws_size,
                              hipStream_t stream)
{
  (void)in_sizes; (void)n_in; (void)out_size; (void)ws_size;
  const float* x    = (const float*)d_in[0];
  const int*   mask = (const int*)  d_in[1];
  const float* wq = (const float*)d_in[2];  const float* bq = (const float*)d_in[3];
  const float* wk = (const float*)d_in[4];  const float* bk = (const float*)d_in[5];
  const float* wv = (const float*)d_in[6];  const float* bv = (const float*)d_in[7];
  const float* wo = (const float*)d_in[8];  const float* bo = (const float*)d_in[9];
  const float* w1 = (const float*)d_in[10]; const float* b1 = (const float*)d_in[11];
  const float* w2 = (const float*)d_in[12]; const float* b2 = (const float*)d_in[13];
  const float* alpha1 = (const float*)d_in[14]; const float* beta1 = (const float*)d_in[15];
  const float* alpha2 = (const float*)d_in[16]; const float* beta2 = (const float*)d_in[17];
  float* out = (float*)d_out;

  // ---- workspace layout (bytes) ----
  const long WSZ = (long)768 * 768 * 2;        // 1,179,648
  const long W1SZ = (long)3072 * 768 * 2;      // 4,718,592
  const long SZB = (long)8192 * 768 * 2;       // 12,582,912
  char* ws = (char*)d_ws;
  bf16* wqkvb = (bf16*)(ws);                   // wq|wk|wv contiguous [2304,768]
  bf16* wob = (bf16*)(ws + 3 * WSZ);
  bf16* w1b = (bf16*)(ws + 4 * WSZ);
  bf16* w2b = (bf16*)(ws + 4 * WSZ + W1SZ);
  float* bqkv   = (float*)(ws + 4 * WSZ + 2 * W1SZ);             // 2304 f32
  float* bias_g = (float*)(ws + 4 * WSZ + 2 * W1SZ + 9216);      // 8192 f32
  const long BASE = 16l << 20;
  bf16* h   = (bf16*)(ws + BASE);            // LN output (reused as h2)
  bf16* qws = (bf16*)(ws + BASE + 1 * SZB);  // Q [B,H,S,64] (pre-scaled 1/8)
  bf16* kws = (bf16*)(ws + BASE + 2 * SZB);  // K [B,H,S,64]
  bf16* vtw = (bf16*)(ws + BASE + 3 * SZB);  // V^T [B,H,64,S]
  bf16* ctx = (bf16*)(ws + BASE + 4 * SZB);  // attention context [B,S,768]
  bf16* x1  = (bf16*)(ws + BASE + 5 * SZB);  // residual-1 output (bf16)
  bf16* ff  = qws;                           // FFN hidden [8192,3072]

  dim3 blk(256);

  hipLaunchKernelGGL(prep_all, dim3(6912), blk, 0, stream,
                     wq, wk, wv, wo, w1, w2, bq, bk, bv, mask,
                     wqkvb, wob, w1b, w2b, bqkv, bias_g);

  hipLaunchKernelGGL((ln_kernel<float>), dim3(8192), blk, 0, stream, x, h, alpha1, beta1);
  hipLaunchKernelGGL(gemm_qkv, dim3(64, 18), blk, 0, stream, h, wqkvb, bqkv, qws, kws, vtw);
  hipLaunchKernelGGL(attn_kernel, dim3(32, 24), blk, 0, stream, qws, kws, vtw, bias_g, ctx);
  hipLaunchKernelGGL((gemm_bt<4, float, bf16>), dim3(64, 6), blk, 0, stream, ctx, wob, bo, x, x1, 8192, 768, 768);
  hipLaunchKernelGGL((ln_kernel<bf16>), dim3(8192), blk, 0, stream, x1, h, alpha2, beta2);
  hipLaunchKernelGGL((gemm_bt<1, float, bf16>), dim3(64, 24), blk, 0, stream, h, w1b, b1, (const float*)nullptr, ff, 8192, 3072, 768);
  hipLaunchKernelGGL((gemm_bt<4, bf16, float>), dim3(64, 6), blk, 0, stream, ff, w2b, b2, x1, out, 8192, 768, 3072);
}

// Round 8
// 437.178 us; speedup vs baseline: 1.2316x; 1.1291x over previous
//
#include <hip/hip_runtime.h>
#include <hip/hip_bf16.h>
#include <math.h>

// EncoderBlock: B=2, S=4096, D_MODEL=768, H=12, dk=64, D_FF=3072.
// Inputs fp32 (mask int32), output fp32. Internal compute bf16 MFMA.
// Round 8: key compaction — ~50% of keys are masked (score -1e9 -> p==0.0
// exactly in fp32), so attention runs only over compacted valid keys.
// Attn core is the round-7 (round-4) proven structure, loop bound nch[b].

typedef __hip_bfloat16 bf16;
typedef short short8 __attribute__((ext_vector_type(8)));   // 8 bf16 (4 VGPRs)
typedef short short4v __attribute__((ext_vector_type(4)));  // 4 bf16 (8B)
typedef float f32x4 __attribute__((ext_vector_type(4)));

#define MFMA(A, B, C) __builtin_amdgcn_mfma_f32_16x16x32_bf16(A, B, C, 0, 0, 0)

__device__ __forceinline__ void gl_lds16(const void* g, void* l) {
  __builtin_amdgcn_global_load_lds(
      (__attribute__((address_space(1))) void*)g,
      (__attribute__((address_space(3))) void*)l, 16, 0, 0);
}

__device__ __forceinline__ short f2b(float f) {
  bf16 h = __float2bfloat16(f);
  return *reinterpret_cast<short*>(&h);
}

// ---------------- fused prep ------------------------------------------------
// blocks 0..1: per-batch key scan -> pos (sentinel -1), nch, biasc, pad-fill
//              of compacted K rows / V^T columns.
// blocks 2..6913: weight fp32->bf16 conversion (+ QKV bias concat).
__global__ __launch_bounds__(256)
void prep_all(const float* __restrict__ wq, const float* __restrict__ wk,
              const float* __restrict__ wv, const float* __restrict__ wo,
              const float* __restrict__ w1, const float* __restrict__ w2,
              const float* __restrict__ bq, const float* __restrict__ bk,
              const float* __restrict__ bv, const int* __restrict__ mask,
              bf16* __restrict__ wqkvb, bf16* __restrict__ wob,
              bf16* __restrict__ w1b, bf16* __restrict__ w2b,
              float* __restrict__ bqkv,
              int* __restrict__ pos_g, int* __restrict__ nch_g,
              float* __restrict__ biasc,
              bf16* __restrict__ kc, bf16* __restrict__ vtc)
{
  const int t = threadIdx.x;
  if (blockIdx.x < 2) {
    // ---- scan block for batch b ----
    const int b = blockIdx.x;
    const int* mb = mask + b * 4096;
    __shared__ int lsum[256];
    int loc = 0;
    int mv[16];
#pragma unroll
    for (int j = 0; j < 16; j++) { mv[j] = mb[t * 16 + j] ? 1 : 0; loc += mv[j]; }
    lsum[t] = loc;
    __syncthreads();
    // Hillis-Steele inclusive scan
    for (int off = 1; off < 256; off <<= 1) {
      int v = (t >= off) ? lsum[t - off] : 0;
      __syncthreads();
      lsum[t] += v;
      __syncthreads();
    }
    const int nvalid = lsum[255];
    int base = lsum[t] - loc;   // exclusive prefix of this thread's group
#pragma unroll
    for (int j = 0; j < 16; j++) {
      pos_g[b * 4096 + t * 16 + j] = mv[j] ? base : -1;
      if (mv[j]) base++;
    }
    const int npad = (nvalid + 63) & ~63;
    if (t == 0) nch_g[b] = npad >> 6;
    // compacted-domain bias: 0 for valid slots, -1e9 for pad slots
    for (int i = t; i < 4096; i += 256)
      biasc[b * 4096 + i] = (i < nvalid) ? 0.f : -1e9f;
    const int npv = npad - nvalid;   // 0..63 pad rows
    if (npv > 0) {
      // zero-fill pad rows of compacted K: [b*12+hh][nvalid..npad)[64 d]
      const int krows = 12 * npv;
      const short8 z = {};
      for (int task = t; task < krows * 8; task += 256) {
        const int rr = task >> 3, cc = task & 7;
        const int hh = rr / npv, r = nvalid + rr % npv;
        *(short8*)&kc[(((long)(b * 12 + hh) * 4096) + r) * 64 + cc * 8] = z;
      }
      // zero-fill pad cols of compacted V^T: [b*12+hh][64 d][nvalid..npad)
      const int vrows = 12 * 64;
      for (int task = t; task < vrows * npv; task += 256) {
        const int row = task / npv, j = nvalid + task % npv;
        const int hh = row >> 6, d = row & 63;
        vtc[((long)((b * 12 + hh) * 64 + d)) * 4096 + j] = __float2bfloat16(0.f);
      }
    }
    return;
  }
  // ---- conversion blocks ----
  const int i = (blockIdx.x - 2) * 256 + t;   // float4 index, exact range
  const int W = 147456;   // 768*768/4
  const int F = 589824;   // 3072*768/4
  const float* src; bf16* dst; int off;
  if (i < W)          { src = wq; dst = wqkvb;           off = i; }
  else if (i < 2*W)   { src = wk; dst = wqkvb + 589824;  off = i - W; }
  else if (i < 3*W)   { src = wv; dst = wqkvb + 1179648; off = i - 2*W; }
  else if (i < 4*W)   { src = wo; dst = wob;             off = i - 3*W; }
  else if (i < 4*W+F) { src = w1; dst = w1b;             off = i - 4*W; }
  else                { src = w2; dst = w2b;             off = i - 4*W - F; }
  float4 v = ((const float4*)src)[off];
  short4v o;
  o.x = f2b(v.x); o.y = f2b(v.y); o.z = f2b(v.z); o.w = f2b(v.w);
  ((short4v*)dst)[off] = o;
  if (i < 2304)
    bqkv[i] = (i < 768) ? bq[i] : (i < 1536 ? bk[i - 768] : bv[i - 1536]);
}

// ---------------- LayerNorm (scalar alpha/beta, unbiased std) ----------------
template<typename INT>
__global__ __launch_bounds__(256)
void ln_kernel(const INT* __restrict__ x, bf16* __restrict__ out,
               const float* __restrict__ alpha, const float* __restrict__ beta)
{
  const int row = blockIdx.x;
  const long base = (long)row * 768;
  const int t = threadIdx.x;
  float v[3]; float s = 0.f, ss = 0.f;
#pragma unroll
  for (int i = 0; i < 3; i++) {
    v[i] = (float)x[base + t + i * 256];
    s += v[i]; ss += v[i] * v[i];
  }
#pragma unroll
  for (int off = 32; off > 0; off >>= 1) {
    s  += __shfl_down(s, off);
    ss += __shfl_down(ss, off);
  }
  __shared__ float red[8];
  __shared__ float stats[2];
  const int w = t >> 6;
  if ((t & 63) == 0) { red[w] = s; red[4 + w] = ss; }
  __syncthreads();
  if (t == 0) {
    float S  = red[0] + red[1] + red[2] + red[3];
    float SS = red[4] + red[5] + red[6] + red[7];
    float mean = S * (1.f / 768.f);
    float var = fmaxf((SS - 768.f * mean * mean) * (1.f / 767.f), 0.f);
    stats[0] = mean;
    stats[1] = 1.f / (sqrtf(var) + 1e-6f);   // 1/(std+eps)
  }
  __syncthreads();
  const float mean = stats[0], rinv = stats[1];
  const float a = alpha[0], b = beta[0];
#pragma unroll
  for (int i = 0; i < 3; i++)
    out[base + t + i * 256] = __float2bfloat16(a * (v[i] - mean) * rinv + b);
}

// ---------------- generic GEMM: C = A*W^T + bias ------------------------------
// MODE: 1 +ReLU | 4 +residual R[m][n]
template<int MODE, typename RT, typename OUTT>
__global__ __launch_bounds__(256)
void gemm_bt(const bf16* __restrict__ A, const bf16* __restrict__ W,
             const float* __restrict__ bias, const RT* __restrict__ R,
             OUTT* __restrict__ Cout, int M, int N, int K)
{
  __shared__ __align__(16) bf16 sA[128 * 32];
  __shared__ __align__(16) bf16 sB[128 * 32];
  const int t = threadIdx.x;
  const int w = t >> 6, lane = t & 63;
  const int lr = lane & 15, quad = lane >> 4;
  const int tm = blockIdx.x * 128, tn = blockIdx.y * 128;
  const int wm = (w >> 1) * 64, wn = (w & 1) * 64;

  const int srow = w * 16 + (lane >> 2);
  const int scol = (lane & 3) * 8;
  const bf16* Ap = A + (long)(tm + srow) * K + scol;
  const bf16* Wp = W + (long)(tn + srow) * K + scol;
  bf16* sAp = &sA[srow * 32 + scol];
  bf16* sBp = &sB[srow * 32 + scol];
  const long half = (long)64 * K;

  f32x4 acc[4][4] = {};

  for (int kb = 0; kb < K; kb += 32) {
    gl_lds16(Ap + kb, sAp);
    gl_lds16(Ap + kb + half, sAp + 64 * 32);
    gl_lds16(Wp + kb, sBp);
    gl_lds16(Wp + kb + half, sBp + 64 * 32);
    __syncthreads();
    short8 af[4], bfr[4];
#pragma unroll
    for (int i = 0; i < 4; i++)
      af[i] = *(const short8*)&sA[(wm + i * 16 + lr) * 32 + quad * 8];
#pragma unroll
    for (int j = 0; j < 4; j++)
      bfr[j] = *(const short8*)&sB[(wn + j * 16 + lr) * 32 + quad * 8];
#pragma unroll
    for (int i = 0; i < 4; i++)
#pragma unroll
      for (int j = 0; j < 4; j++)
        acc[i][j] = MFMA(af[i], bfr[j], acc[i][j]);
    __syncthreads();
  }

#pragma unroll
  for (int i = 0; i < 4; i++) {
#pragma unroll
    for (int j = 0; j < 4; j++) {
      const int col = tn + wn + j * 16 + lr;
      const float bv = bias[col];
#pragma unroll
      for (int r = 0; r < 4; r++) {
        const int m = tm + wm + i * 16 + quad * 4 + r;
        float vv = acc[i][j][r] + bv;
        if (MODE == 1) vv = fmaxf(vv, 0.f);
        if (MODE == 4) vv += (float)R[(long)m * N + col];
        Cout[(long)m * N + col] = (OUTT)vv;
      }
    }
  }
}

// ---------------- fused QKV GEMM: N=2304, region-scatter epilogue -----------
// cols [0,768): Q *0.125 -> [B,H,S,64]; [768,1536): K -> compacted rows
// (pos_g, sentinel -1 = masked, skip); [1536,2304): V -> compacted V^T cols.
__global__ __launch_bounds__(256)
void gemm_qkv(const bf16* __restrict__ A, const bf16* __restrict__ W,
              const float* __restrict__ bias, const int* __restrict__ pos_g,
              bf16* __restrict__ Qo, bf16* __restrict__ Kc, bf16* __restrict__ Vtc)
{
  const int K = 768;
  __shared__ __align__(16) bf16 sA[128 * 32];
  __shared__ __align__(16) bf16 sB[128 * 32];
  const int t = threadIdx.x;
  const int w = t >> 6, lane = t & 63;
  const int lr = lane & 15, quad = lane >> 4;
  const int tm = blockIdx.x * 128, tn = blockIdx.y * 128;
  const int wm = (w >> 1) * 64, wn = (w & 1) * 64;

  const int srow = w * 16 + (lane >> 2);
  const int scol = (lane & 3) * 8;
  const bf16* Ap = A + (long)(tm + srow) * K + scol;
  const bf16* Wp = W + (long)(tn + srow) * K + scol;
  bf16* sAp = &sA[srow * 32 + scol];
  bf16* sBp = &sB[srow * 32 + scol];
  const long half = (long)64 * K;

  f32x4 acc[4][4] = {};

  for (int kb = 0; kb < K; kb += 32) {
    gl_lds16(Ap + kb, sAp);
    gl_lds16(Ap + kb + half, sAp + 64 * 32);
    gl_lds16(Wp + kb, sBp);
    gl_lds16(Wp + kb + half, sBp + 64 * 32);
    __syncthreads();
    short8 af[4], bfr[4];
#pragma unroll
    for (int i = 0; i < 4; i++)
      af[i] = *(const short8*)&sA[(wm + i * 16 + lr) * 32 + quad * 8];
#pragma unroll
    for (int j = 0; j < 4; j++)
      bfr[j] = *(const short8*)&sB[(wn + j * 16 + lr) * 32 + quad * 8];
#pragma unroll
    for (int i = 0; i < 4; i++)
#pragma unroll
      for (int j = 0; j < 4; j++)
        acc[i][j] = MFMA(af[i], bfr[j], acc[i][j]);
    __syncthreads();
  }

  const int region = (tn >= 1536) ? 2 : (tn >= 768 ? 1 : 0);  // block-uniform
#pragma unroll
  for (int i = 0; i < 4; i++) {
#pragma unroll
    for (int j = 0; j < 4; j++) {
      const int col = tn + wn + j * 16 + lr;
      const int c768 = col - region * 768;
      const int hh = c768 >> 6, d = c768 & 63;
      const float bv = bias[col];
#pragma unroll
      for (int r = 0; r < 4; r++) {
        const int m = tm + wm + i * 16 + quad * 4 + r;
        const int bb = m >> 12, sdx = m & 4095;
        float vv = acc[i][j][r] + bv;
        if (region == 0) {
          vv *= 0.125f;   // exact pow2: folds 1/sqrt(dk) into Q
          Qo[((long)(bb * 12 + hh) * 4096 + sdx) * 64 + d] = __float2bfloat16(vv);
        } else {
          const int p_ = pos_g[bb * 4096 + sdx];
          if (p_ >= 0) {
            if (region == 1)
              Kc[((long)(bb * 12 + hh) * 4096 + p_) * 64 + d] = __float2bfloat16(vv);
            else
              Vtc[((long)(bb * 12 + hh) * 64 + d) * 4096 + p_] = __float2bfloat16(vv);
          }
        }
      }
    }
  }
}

// ---------------- Flash attention over compacted keys ------------------------
// Round-7 proven core; K-loop runs nch[b] chunks of 64 compacted keys.
// Q (pre-scaled 0.125): [B,H,S,64]; Kc: [B,H,4096cap,64]; Vtc: [B,H,64,4096cap].
// biasc: 0 for valid slots, -1e9 for pad slots. Grid (32,24), LDS 36864 B.
__global__ __launch_bounds__(256)
void attn_kernel(const bf16* __restrict__ Q, const bf16* __restrict__ Kg,
                 const bf16* __restrict__ Vt, const float* __restrict__ biasc,
                 const int* __restrict__ nch_g, bf16* __restrict__ ctx)
{
  __shared__ __align__(16) bf16 sK[64 * 72];      // [key][d], stride 72
  __shared__ __align__(16) bf16 sV[64 * 72];      // [d][key], stride 72
  __shared__ __align__(16) bf16 sP[4][32 * 72];   // per-wave P [q][key]

  const int t = threadIdx.x, w = t >> 6, lane = t & 63;
  const int lr = lane & 15, quad = lane >> 4;
  const int bh = blockIdx.y, b = bh / 12, hh = bh % 12;
  const int qb = blockIdx.x * 128 + w * 32;       // this wave's 32 queries
  const long bh_s = (long)bh * 4096;
  const float* bg = biasc + b * 4096;
  const int nch = nch_g[b];

  short8 qf[2][2];
#pragma unroll
  for (int qt = 0; qt < 2; qt++) {
    const bf16* qp = Q + (bh_s + qb + qt * 16 + lr) * 64 + quad * 8;
    qf[qt][0] = *(const short8*)qp;
    qf[qt][1] = *(const short8*)(qp + 32);
  }

  float l_part[2][4] = {};
  f32x4 O[2][4] = {};

  const int srow = t >> 3;          // 0..31
  const int scol = (t & 7) * 8;     // 0..56
  const bf16* kp0 = Kg + (bh_s + srow) * 64 + scol;
  const bf16* kp1 = Kg + (bh_s + srow + 32) * 64 + scol;
  const bf16* vp0 = Vt + ((long)bh * 64 + srow) * 4096 + scol;
  const bf16* vp1 = Vt + ((long)bh * 64 + srow + 32) * 4096 + scol;

  for (int ci = 0; ci < nch; ci++) {
    const int kc = ci * 64;
    short8 k0 = *(const short8*)(kp0 + (long)kc * 64);
    short8 k1 = *(const short8*)(kp1 + (long)kc * 64);
    short8 v0 = *(const short8*)(vp0 + kc);
    short8 v1 = *(const short8*)(vp1 + kc);
    float bb[4];
#pragma unroll
    for (int kt = 0; kt < 4; kt++) bb[kt] = bg[kc + kt * 16 + lr];
    __syncthreads();   // previous chunk's LDS reads complete
    *(short8*)&sK[srow * 72 + scol]        = k0;
    *(short8*)&sK[(srow + 32) * 72 + scol] = k1;
    *(short8*)&sV[srow * 72 + scol]        = v0;
    *(short8*)&sV[(srow + 32) * 72 + scol] = v1;
    __syncthreads();   // staged data visible

    // ---- S = Q' K^T : 2 qtiles x 4 ktiles x 2 d-halves = 16 MFMA ----
    f32x4 s[2][4] = {};
#pragma unroll
    for (int kt = 0; kt < 4; kt++) {
      short8 kfa = *(const short8*)&sK[(kt * 16 + lr) * 72 + quad * 8];
      short8 kfb = *(const short8*)&sK[(kt * 16 + lr) * 72 + 32 + quad * 8];
      s[0][kt] = MFMA(qf[0][0], kfa, s[0][kt]);
      s[0][kt] = MFMA(qf[0][1], kfb, s[0][kt]);
      s[1][kt] = MFMA(qf[1][0], kfa, s[1][kt]);
      s[1][kt] = MFMA(qf[1][1], kfb, s[1][kt]);
    }

    // ---- p = exp(s + bias); accumulate l; P -> wave-private LDS ----
#pragma unroll
    for (int kt = 0; kt < 4; kt++) {
#pragma unroll
      for (int qt = 0; qt < 2; qt++) {
#pragma unroll
        for (int r = 0; r < 4; r++) {
          const float p = __expf(s[qt][kt][r] + bb[kt]);
          l_part[qt][r] += p;
          sP[w][(qt * 16 + quad * 4 + r) * 72 + kt * 16 + lr] = __float2bfloat16(p);
        }
      }
    }
    // wave-private sP: lgkmcnt ordering only, no barrier needed

    // ---- O += P V : 2 qtiles x 4 d-blocks x 2 k-halves = 16 MFMA ----
    short8 pf[2][2];
#pragma unroll
    for (int qt = 0; qt < 2; qt++) {
      pf[qt][0] = *(const short8*)&sP[w][(qt * 16 + lr) * 72 + quad * 8];
      pf[qt][1] = *(const short8*)&sP[w][(qt * 16 + lr) * 72 + 32 + quad * 8];
    }
#pragma unroll
    for (int j = 0; j < 4; j++) {
      short8 vfa = *(const short8*)&sV[(j * 16 + lr) * 72 + quad * 8];
      short8 vfb = *(const short8*)&sV[(j * 16 + lr) * 72 + 32 + quad * 8];
      O[0][j] = MFMA(pf[0][0], vfa, O[0][j]);
      O[0][j] = MFMA(pf[0][1], vfb, O[0][j]);
      O[1][j] = MFMA(pf[1][0], vfa, O[1][j]);
      O[1][j] = MFMA(pf[1][1], vfb, O[1][j]);
    }
  }

  // epilogue: reduce l over the 16 lr-lanes, normalize, store
#pragma unroll
  for (int qt = 0; qt < 2; qt++) {
#pragma unroll
    for (int r = 0; r < 4; r++) {
      float l = l_part[qt][r];
#pragma unroll
      for (int off = 1; off < 16; off <<= 1) l += __shfl_xor(l, off, 16);
      const float il = (l > 0.f) ? 1.f / l : 0.f;
      const int q = qb + qt * 16 + quad * 4 + r;
      bf16* cp = ctx + ((long)(b * 4096 + q)) * 768 + hh * 64 + lr;
#pragma unroll
      for (int j = 0; j < 4; j++)
        cp[j * 16] = __float2bfloat16(O[qt][j][r] * il);
    }
  }
}

// ---------------------------------------------------------------------------
extern "C" void kernel_launch(void* const* d_in, const int* in_sizes, int n_in,
                              void* d_out, int out_size, void* d_ws, size_t ws_size,
                              hipStream_t stream)
{
  (void)in_sizes; (void)n_in; (void)out_size; (void)ws_size;
  const float* x    = (const float*)d_in[0];
  const int*   mask = (const int*)  d_in[1];
  const float* wq = (const float*)d_in[2];  const float* bq = (const float*)d_in[3];
  const float* wk = (const float*)d_in[4];  const float* bk = (const float*)d_in[5];
  const float* wv = (const float*)d_in[6];  const float* bv = (const float*)d_in[7];
  const float* wo = (const float*)d_in[8];  const float* bo = (const float*)d_in[9];
  const float* w1 = (const float*)d_in[10]; const float* b1 = (const float*)d_in[11];
  const float* w2 = (const float*)d_in[12]; const float* b2 = (const float*)d_in[13];
  const float* alpha1 = (const float*)d_in[14]; const float* beta1 = (const float*)d_in[15];
  const float* alpha2 = (const float*)d_in[16]; const float* beta2 = (const float*)d_in[17];
  float* out = (float*)d_out;

  // ---- workspace layout (bytes) ----
  const long WSZ = (long)768 * 768 * 2;        // 1,179,648
  const long W1SZ = (long)3072 * 768 * 2;      // 4,718,592
  const long SZB = (long)8192 * 768 * 2;       // 12,582,912
  char* ws = (char*)d_ws;
  bf16* wqkvb = (bf16*)(ws);                   // wq|wk|wv contiguous [2304,768]
  bf16* wob = (bf16*)(ws + 3 * WSZ);
  bf16* w1b = (bf16*)(ws + 4 * WSZ);
  bf16* w2b = (bf16*)(ws + 4 * WSZ + W1SZ);
  char* aux = ws + 4 * WSZ + 2 * W1SZ;
  float* bqkv   = (float*)(aux);               // 2304 f32
  int*   pos_g  = (int*)(aux + 16384);         // 2*4096 int
  float* biasc  = (float*)(aux + 49152);       // 2*4096 f32
  int*   nch_g  = (int*)(aux + 81920);         // 2 int
  const long BASE = 16l << 20;
  bf16* h   = (bf16*)(ws + BASE);            // LN output (reused as h2)
  bf16* qws = (bf16*)(ws + BASE + 1 * SZB);  // Q [B,H,S,64] (pre-scaled 1/8)
  bf16* kcw = (bf16*)(ws + BASE + 2 * SZB);  // compacted K [B,H,4096cap,64]
  bf16* vtc = (bf16*)(ws + BASE + 3 * SZB);  // compacted V^T [B,H,64,4096cap]
  bf16* ctx = (bf16*)(ws + BASE + 4 * SZB);  // attention context [B,S,768]
  bf16* x1  = (bf16*)(ws + BASE + 5 * SZB);  // residual-1 output (bf16)
  bf16* ff  = qws;                           // FFN hidden [8192,3072]

  dim3 blk(256);

  hipLaunchKernelGGL(prep_all, dim3(6914), blk, 0, stream,
                     wq, wk, wv, wo, w1, w2, bq, bk, bv, mask,
                     wqkvb, wob, w1b, w2b, bqkv, pos_g, nch_g, biasc, kcw, vtc);

  hipLaunchKernelGGL((ln_kernel<float>), dim3(8192), blk, 0, stream, x, h, alpha1, beta1);
  hipLaunchKernelGGL(gemm_qkv, dim3(64, 18), blk, 0, stream, h, wqkvb, bqkv, pos_g, qws, kcw, vtc);
  hipLaunchKernelGGL(attn_kernel, dim3(32, 24), blk, 0, stream, qws, kcw, vtc, biasc, nch_g, ctx);
  hipLaunchKernelGGL((gemm_bt<4, float, bf16>), dim3(64, 6), blk, 0, stream, ctx, wob, bo, x, x1, 8192, 768, 768);
  hipLaunchKernelGGL((ln_kernel<bf16>), dim3(8192), blk, 0, stream, x1, h, alpha2, beta2);
  hipLaunchKernelGGL((gemm_bt<1, float, bf16>), dim3(64, 24), blk, 0, stream, h, w1b, b1, (const float*)nullptr, ff, 8192, 3072, 768);
  hipLaunchKernelGGL((gemm_bt<4, bf16, float>), dim3(64, 6), blk, 0, stream, ff, w2b, b2, x1, out, 8192, 768, 3072);
}

// Round 9
// 422.173 us; speedup vs baseline: 1.2754x; 1.0355x over previous
//
#include <hip/hip_runtime.h>
#include <hip/hip_bf16.h>
#include <math.h>

// EncoderBlock: B=2, S=4096, D_MODEL=768, H=12, dk=64, D_FF=3072.
// Inputs fp32 (mask int32), output fp32. Internal compute bf16 MFMA.
// Round 9: N=768 GEMMs (O-proj, FFN2) re-tiled to 64x128 -> grid 768 blocks
// (3.0/CU, no half-wave idle). Attn (compacted keys) untouched from round 8.

typedef __hip_bfloat16 bf16;
typedef short short8 __attribute__((ext_vector_type(8)));   // 8 bf16 (4 VGPRs)
typedef short short4v __attribute__((ext_vector_type(4)));  // 4 bf16 (8B)
typedef float f32x4 __attribute__((ext_vector_type(4)));

#define MFMA(A, B, C) __builtin_amdgcn_mfma_f32_16x16x32_bf16(A, B, C, 0, 0, 0)

__device__ __forceinline__ void gl_lds16(const void* g, void* l) {
  __builtin_amdgcn_global_load_lds(
      (__attribute__((address_space(1))) void*)g,
      (__attribute__((address_space(3))) void*)l, 16, 0, 0);
}

__device__ __forceinline__ short f2b(float f) {
  bf16 h = __float2bfloat16(f);
  return *reinterpret_cast<short*>(&h);
}

// ---------------- fused prep ------------------------------------------------
// blocks 0..1: per-batch key scan -> pos (sentinel -1), nch, biasc, pad-fill
//              of compacted K rows / V^T columns.
// blocks 2..6913: weight fp32->bf16 conversion (+ QKV bias concat).
__global__ __launch_bounds__(256)
void prep_all(const float* __restrict__ wq, const float* __restrict__ wk,
              const float* __restrict__ wv, const float* __restrict__ wo,
              const float* __restrict__ w1, const float* __restrict__ w2,
              const float* __restrict__ bq, const float* __restrict__ bk,
              const float* __restrict__ bv, const int* __restrict__ mask,
              bf16* __restrict__ wqkvb, bf16* __restrict__ wob,
              bf16* __restrict__ w1b, bf16* __restrict__ w2b,
              float* __restrict__ bqkv,
              int* __restrict__ pos_g, int* __restrict__ nch_g,
              float* __restrict__ biasc,
              bf16* __restrict__ kc, bf16* __restrict__ vtc)
{
  const int t = threadIdx.x;
  if (blockIdx.x < 2) {
    const int b = blockIdx.x;
    const int* mb = mask + b * 4096;
    __shared__ int lsum[256];
    int loc = 0;
    int mv[16];
#pragma unroll
    for (int j = 0; j < 16; j++) { mv[j] = mb[t * 16 + j] ? 1 : 0; loc += mv[j]; }
    lsum[t] = loc;
    __syncthreads();
    for (int off = 1; off < 256; off <<= 1) {
      int v = (t >= off) ? lsum[t - off] : 0;
      __syncthreads();
      lsum[t] += v;
      __syncthreads();
    }
    const int nvalid = lsum[255];
    int base = lsum[t] - loc;
#pragma unroll
    for (int j = 0; j < 16; j++) {
      pos_g[b * 4096 + t * 16 + j] = mv[j] ? base : -1;
      if (mv[j]) base++;
    }
    const int npad = (nvalid + 63) & ~63;
    if (t == 0) nch_g[b] = npad >> 6;
    for (int i = t; i < 4096; i += 256)
      biasc[b * 4096 + i] = (i < nvalid) ? 0.f : -1e9f;
    const int npv = npad - nvalid;
    if (npv > 0) {
      const int krows = 12 * npv;
      const short8 z = {};
      for (int task = t; task < krows * 8; task += 256) {
        const int rr = task >> 3, cc = task & 7;
        const int hh = rr / npv, r = nvalid + rr % npv;
        *(short8*)&kc[(((long)(b * 12 + hh) * 4096) + r) * 64 + cc * 8] = z;
      }
      const int vrows = 12 * 64;
      for (int task = t; task < vrows * npv; task += 256) {
        const int row = task / npv, j = nvalid + task % npv;
        const int hh = row >> 6, d = row & 63;
        vtc[((long)((b * 12 + hh) * 64 + d)) * 4096 + j] = __float2bfloat16(0.f);
      }
    }
    return;
  }
  const int i = (blockIdx.x - 2) * 256 + t;
  const int W = 147456;   // 768*768/4
  const int F = 589824;   // 3072*768/4
  const float* src; bf16* dst; int off;
  if (i < W)          { src = wq; dst = wqkvb;           off = i; }
  else if (i < 2*W)   { src = wk; dst = wqkvb + 589824;  off = i - W; }
  else if (i < 3*W)   { src = wv; dst = wqkvb + 1179648; off = i - 2*W; }
  else if (i < 4*W)   { src = wo; dst = wob;             off = i - 3*W; }
  else if (i < 4*W+F) { src = w1; dst = w1b;             off = i - 4*W; }
  else                { src = w2; dst = w2b;             off = i - 4*W - F; }
  float4 v = ((const float4*)src)[off];
  short4v o;
  o.x = f2b(v.x); o.y = f2b(v.y); o.z = f2b(v.z); o.w = f2b(v.w);
  ((short4v*)dst)[off] = o;
  if (i < 2304)
    bqkv[i] = (i < 768) ? bq[i] : (i < 1536 ? bk[i - 768] : bv[i - 1536]);
}

// ---------------- LayerNorm (scalar alpha/beta, unbiased std) ----------------
template<typename INT>
__global__ __launch_bounds__(256)
void ln_kernel(const INT* __restrict__ x, bf16* __restrict__ out,
               const float* __restrict__ alpha, const float* __restrict__ beta)
{
  const int row = blockIdx.x;
  const long base = (long)row * 768;
  const int t = threadIdx.x;
  float v[3]; float s = 0.f, ss = 0.f;
#pragma unroll
  for (int i = 0; i < 3; i++) {
    v[i] = (float)x[base + t + i * 256];
    s += v[i]; ss += v[i] * v[i];
  }
#pragma unroll
  for (int off = 32; off > 0; off >>= 1) {
    s  += __shfl_down(s, off);
    ss += __shfl_down(ss, off);
  }
  __shared__ float red[8];
  __shared__ float stats[2];
  const int w = t >> 6;
  if ((t & 63) == 0) { red[w] = s; red[4 + w] = ss; }
  __syncthreads();
  if (t == 0) {
    float S  = red[0] + red[1] + red[2] + red[3];
    float SS = red[4] + red[5] + red[6] + red[7];
    float mean = S * (1.f / 768.f);
    float var = fmaxf((SS - 768.f * mean * mean) * (1.f / 767.f), 0.f);
    stats[0] = mean;
    stats[1] = 1.f / (sqrtf(var) + 1e-6f);
  }
  __syncthreads();
  const float mean = stats[0], rinv = stats[1];
  const float a = alpha[0], b = beta[0];
#pragma unroll
  for (int i = 0; i < 3; i++)
    out[base + t + i * 256] = __float2bfloat16(a * (v[i] - mean) * rinv + b);
}

// ---------------- generic GEMM: C = A*W^T + bias, tile TM x 128 --------------
// TM in {128, 64}. MODE: 1 +ReLU | 4 +residual R[m][n]
template<int MODE, int TM, typename RT, typename OUTT>
__global__ __launch_bounds__(256)
void gemm_bt(const bf16* __restrict__ A, const bf16* __restrict__ W,
             const float* __restrict__ bias, const RT* __restrict__ R,
             OUTT* __restrict__ Cout, int M, int N, int K)
{
  constexpr int MI = TM / 32;                 // acc row-tiles per wave (4 or 2)
  __shared__ __align__(16) bf16 sA[TM * 32];
  __shared__ __align__(16) bf16 sB[128 * 32];
  const int t = threadIdx.x;
  const int w = t >> 6, lane = t & 63;
  const int lr = lane & 15, quad = lane >> 4;
  const int tm = blockIdx.x * TM, tn = blockIdx.y * 128;
  const int wm = (w >> 1) * (MI * 16), wn = (w & 1) * 64;

  const int srow = w * 16 + (lane >> 2);      // 0..63
  const int scol = (lane & 3) * 8;
  const bf16* Ap = A + (long)(tm + srow) * K + scol;
  const bf16* Wp = W + (long)(tn + srow) * K + scol;
  bf16* sAp = &sA[srow * 32 + scol];
  bf16* sBp = &sB[srow * 32 + scol];
  const long half = (long)64 * K;

  f32x4 acc[MI][4] = {};

  for (int kb = 0; kb < K; kb += 32) {
    gl_lds16(Ap + kb, sAp);
    if (TM == 128) gl_lds16(Ap + kb + half, sAp + 64 * 32);
    gl_lds16(Wp + kb, sBp);
    gl_lds16(Wp + kb + half, sBp + 64 * 32);
    __syncthreads();
    short8 af[MI], bfr[4];
#pragma unroll
    for (int i = 0; i < MI; i++)
      af[i] = *(const short8*)&sA[(wm + i * 16 + lr) * 32 + quad * 8];
#pragma unroll
    for (int j = 0; j < 4; j++)
      bfr[j] = *(const short8*)&sB[(wn + j * 16 + lr) * 32 + quad * 8];
#pragma unroll
    for (int i = 0; i < MI; i++)
#pragma unroll
      for (int j = 0; j < 4; j++)
        acc[i][j] = MFMA(af[i], bfr[j], acc[i][j]);
    __syncthreads();
  }

#pragma unroll
  for (int i = 0; i < MI; i++) {
#pragma unroll
    for (int j = 0; j < 4; j++) {
      const int col = tn + wn + j * 16 + lr;
      const float bv = bias[col];
#pragma unroll
      for (int r = 0; r < 4; r++) {
        const int m = tm + wm + i * 16 + quad * 4 + r;
        float vv = acc[i][j][r] + bv;
        if (MODE == 1) vv = fmaxf(vv, 0.f);
        if (MODE == 4) vv += (float)R[(long)m * N + col];
        Cout[(long)m * N + col] = (OUTT)vv;
      }
    }
  }
}

// ---------------- fused QKV GEMM: N=2304, region-scatter epilogue -----------
__global__ __launch_bounds__(256)
void gemm_qkv(const bf16* __restrict__ A, const bf16* __restrict__ W,
              const float* __restrict__ bias, const int* __restrict__ pos_g,
              bf16* __restrict__ Qo, bf16* __restrict__ Kc, bf16* __restrict__ Vtc)
{
  const int K = 768;
  __shared__ __align__(16) bf16 sA[128 * 32];
  __shared__ __align__(16) bf16 sB[128 * 32];
  const int t = threadIdx.x;
  const int w = t >> 6, lane = t & 63;
  const int lr = lane & 15, quad = lane >> 4;
  const int tm = blockIdx.x * 128, tn = blockIdx.y * 128;
  const int wm = (w >> 1) * 64, wn = (w & 1) * 64;

  const int srow = w * 16 + (lane >> 2);
  const int scol = (lane & 3) * 8;
  const bf16* Ap = A + (long)(tm + srow) * K + scol;
  const bf16* Wp = W + (long)(tn + srow) * K + scol;
  bf16* sAp = &sA[srow * 32 + scol];
  bf16* sBp = &sB[srow * 32 + scol];
  const long half = (long)64 * K;

  f32x4 acc[4][4] = {};

  for (int kb = 0; kb < K; kb += 32) {
    gl_lds16(Ap + kb, sAp);
    gl_lds16(Ap + kb + half, sAp + 64 * 32);
    gl_lds16(Wp + kb, sBp);
    gl_lds16(Wp + kb + half, sBp + 64 * 32);
    __syncthreads();
    short8 af[4], bfr[4];
#pragma unroll
    for (int i = 0; i < 4; i++)
      af[i] = *(const short8*)&sA[(wm + i * 16 + lr) * 32 + quad * 8];
#pragma unroll
    for (int j = 0; j < 4; j++)
      bfr[j] = *(const short8*)&sB[(wn + j * 16 + lr) * 32 + quad * 8];
#pragma unroll
    for (int i = 0; i < 4; i++)
#pragma unroll
      for (int j = 0; j < 4; j++)
        acc[i][j] = MFMA(af[i], bfr[j], acc[i][j]);
    __syncthreads();
  }

  const int region = (tn >= 1536) ? 2 : (tn >= 768 ? 1 : 0);  // block-uniform
#pragma unroll
  for (int i = 0; i < 4; i++) {
#pragma unroll
    for (int j = 0; j < 4; j++) {
      const int col = tn + wn + j * 16 + lr;
      const int c768 = col - region * 768;
      const int hh = c768 >> 6, d = c768 & 63;
      const float bv = bias[col];
#pragma unroll
      for (int r = 0; r < 4; r++) {
        const int m = tm + wm + i * 16 + quad * 4 + r;
        const int bb = m >> 12, sdx = m & 4095;
        float vv = acc[i][j][r] + bv;
        if (region == 0) {
          vv *= 0.125f;   // exact pow2: folds 1/sqrt(dk) into Q
          Qo[((long)(bb * 12 + hh) * 4096 + sdx) * 64 + d] = __float2bfloat16(vv);
        } else {
          const int p_ = pos_g[bb * 4096 + sdx];
          if (p_ >= 0) {
            if (region == 1)
              Kc[((long)(bb * 12 + hh) * 4096 + p_) * 64 + d] = __float2bfloat16(vv);
            else
              Vtc[((long)(bb * 12 + hh) * 64 + d) * 4096 + p_] = __float2bfloat16(vv);
          }
        }
      }
    }
  }
}

// ---------------- Flash attention over compacted keys (round-8 proven) -------
__global__ __launch_bounds__(256)
void attn_kernel(const bf16* __restrict__ Q, const bf16* __restrict__ Kg,
                 const bf16* __restrict__ Vt, const float* __restrict__ biasc,
                 const int* __restrict__ nch_g, bf16* __restrict__ ctx)
{
  __shared__ __align__(16) bf16 sK[64 * 72];      // [key][d], stride 72
  __shared__ __align__(16) bf16 sV[64 * 72];      // [d][key], stride 72
  __shared__ __align__(16) bf16 sP[4][32 * 72];   // per-wave P [q][key]

  const int t = threadIdx.x, w = t >> 6, lane = t & 63;
  const int lr = lane & 15, quad = lane >> 4;
  const int bh = blockIdx.y, b = bh / 12, hh = bh % 12;
  const int qb = blockIdx.x * 128 + w * 32;
  const long bh_s = (long)bh * 4096;
  const float* bg = biasc + b * 4096;
  const int nch = nch_g[b];

  short8 qf[2][2];
#pragma unroll
  for (int qt = 0; qt < 2; qt++) {
    const bf16* qp = Q + (bh_s + qb + qt * 16 + lr) * 64 + quad * 8;
    qf[qt][0] = *(const short8*)qp;
    qf[qt][1] = *(const short8*)(qp + 32);
  }

  float l_part[2][4] = {};
  f32x4 O[2][4] = {};

  const int srow = t >> 3;
  const int scol = (t & 7) * 8;
  const bf16* kp0 = Kg + (bh_s + srow) * 64 + scol;
  const bf16* kp1 = Kg + (bh_s + srow + 32) * 64 + scol;
  const bf16* vp0 = Vt + ((long)bh * 64 + srow) * 4096 + scol;
  const bf16* vp1 = Vt + ((long)bh * 64 + srow + 32) * 4096 + scol;

  for (int ci = 0; ci < nch; ci++) {
    const int kc = ci * 64;
    short8 k0 = *(const short8*)(kp0 + (long)kc * 64);
    short8 k1 = *(const short8*)(kp1 + (long)kc * 64);
    short8 v0 = *(const short8*)(vp0 + kc);
    short8 v1 = *(const short8*)(vp1 + kc);
    float bb[4];
#pragma unroll
    for (int kt = 0; kt < 4; kt++) bb[kt] = bg[kc + kt * 16 + lr];
    __syncthreads();
    *(short8*)&sK[srow * 72 + scol]        = k0;
    *(short8*)&sK[(srow + 32) * 72 + scol] = k1;
    *(short8*)&sV[srow * 72 + scol]        = v0;
    *(short8*)&sV[(srow + 32) * 72 + scol] = v1;
    __syncthreads();

    f32x4 s[2][4] = {};
#pragma unroll
    for (int kt = 0; kt < 4; kt++) {
      short8 kfa = *(const short8*)&sK[(kt * 16 + lr) * 72 + quad * 8];
      short8 kfb = *(const short8*)&sK[(kt * 16 + lr) * 72 + 32 + quad * 8];
      s[0][kt] = MFMA(qf[0][0], kfa, s[0][kt]);
      s[0][kt] = MFMA(qf[0][1], kfb, s[0][kt]);
      s[1][kt] = MFMA(qf[1][0], kfa, s[1][kt]);
      s[1][kt] = MFMA(qf[1][1], kfb, s[1][kt]);
    }

#pragma unroll
    for (int kt = 0; kt < 4; kt++) {
#pragma unroll
      for (int qt = 0; qt < 2; qt++) {
#pragma unroll
        for (int r = 0; r < 4; r++) {
          const float p = __expf(s[qt][kt][r] + bb[kt]);
          l_part[qt][r] += p;
          sP[w][(qt * 16 + quad * 4 + r) * 72 + kt * 16 + lr] = __float2bfloat16(p);
        }
      }
    }

    short8 pf[2][2];
#pragma unroll
    for (int qt = 0; qt < 2; qt++) {
      pf[qt][0] = *(const short8*)&sP[w][(qt * 16 + lr) * 72 + quad * 8];
      pf[qt][1] = *(const short8*)&sP[w][(qt * 16 + lr) * 72 + 32 + quad * 8];
    }
#pragma unroll
    for (int j = 0; j < 4; j++) {
      short8 vfa = *(const short8*)&sV[(j * 16 + lr) * 72 + quad * 8];
      short8 vfb = *(const short8*)&sV[(j * 16 + lr) * 72 + 32 + quad * 8];
      O[0][j] = MFMA(pf[0][0], vfa, O[0][j]);
      O[0][j] = MFMA(pf[0][1], vfb, O[0][j]);
      O[1][j] = MFMA(pf[1][0], vfa, O[1][j]);
      O[1][j] = MFMA(pf[1][1], vfb, O[1][j]);
    }
  }

#pragma unroll
  for (int qt = 0; qt < 2; qt++) {
#pragma unroll
    for (int r = 0; r < 4; r++) {
      float l = l_part[qt][r];
#pragma unroll
      for (int off = 1; off < 16; off <<= 1) l += __shfl_xor(l, off, 16);
      const float il = (l > 0.f) ? 1.f / l : 0.f;
      const int q = qb + qt * 16 + quad * 4 + r;
      bf16* cp = ctx + ((long)(b * 4096 + q)) * 768 + hh * 64 + lr;
#pragma unroll
      for (int j = 0; j < 4; j++)
        cp[j * 16] = __float2bfloat16(O[qt][j][r] * il);
    }
  }
}

// ---------------------------------------------------------------------------
extern "C" void kernel_launch(void* const* d_in, const int* in_sizes, int n_in,
                              void* d_out, int out_size, void* d_ws, size_t ws_size,
                              hipStream_t stream)
{
  (void)in_sizes; (void)n_in; (void)out_size; (void)ws_size;
  const float* x    = (const float*)d_in[0];
  const int*   mask = (const int*)  d_in[1];
  const float* wq = (const float*)d_in[2];  const float* bq = (const float*)d_in[3];
  const float* wk = (const float*)d_in[4];  const float* bk = (const float*)d_in[5];
  const float* wv = (const float*)d_in[6];  const float* bv = (const float*)d_in[7];
  const float* wo = (const float*)d_in[8];  const float* bo = (const float*)d_in[9];
  const float* w1 = (const float*)d_in[10]; const float* b1 = (const float*)d_in[11];
  const float* w2 = (const float*)d_in[12]; const float* b2 = (const float*)d_in[13];
  const float* alpha1 = (const float*)d_in[14]; const float* beta1 = (const float*)d_in[15];
  const float* alpha2 = (const float*)d_in[16]; const float* beta2 = (const float*)d_in[17];
  float* out = (float*)d_out;

  const long WSZ = (long)768 * 768 * 2;
  const long W1SZ = (long)3072 * 768 * 2;
  const long SZB = (long)8192 * 768 * 2;
  char* ws = (char*)d_ws;
  bf16* wqkvb = (bf16*)(ws);
  bf16* wob = (bf16*)(ws + 3 * WSZ);
  bf16* w1b = (bf16*)(ws + 4 * WSZ);
  bf16* w2b = (bf16*)(ws + 4 * WSZ + W1SZ);
  char* aux = ws + 4 * WSZ + 2 * W1SZ;
  float* bqkv   = (float*)(aux);
  int*   pos_g  = (int*)(aux + 16384);
  float* biasc  = (float*)(aux + 49152);
  int*   nch_g  = (int*)(aux + 81920);
  const long BASE = 16l << 20;
  bf16* h   = (bf16*)(ws + BASE);
  bf16* qws = (bf16*)(ws + BASE + 1 * SZB);
  bf16* kcw = (bf16*)(ws + BASE + 2 * SZB);
  bf16* vtc = (bf16*)(ws + BASE + 3 * SZB);
  bf16* ctx = (bf16*)(ws + BASE + 4 * SZB);
  bf16* x1  = (bf16*)(ws + BASE + 5 * SZB);
  bf16* ff  = qws;

  dim3 blk(256);

  hipLaunchKernelGGL(prep_all, dim3(6914), blk, 0, stream,
                     wq, wk, wv, wo, w1, w2, bq, bk, bv, mask,
                     wqkvb, wob, w1b, w2b, bqkv, pos_g, nch_g, biasc, kcw, vtc);

  hipLaunchKernelGGL((ln_kernel<float>), dim3(8192), blk, 0, stream, x, h, alpha1, beta1);
  hipLaunchKernelGGL(gemm_qkv, dim3(64, 18), blk, 0, stream, h, wqkvb, bqkv, pos_g, qws, kcw, vtc);
  hipLaunchKernelGGL(attn_kernel, dim3(32, 24), blk, 0, stream, qws, kcw, vtc, biasc, nch_g, ctx);
  // N=768 GEMMs: 64x128 tiles -> 768 blocks = 3.0/CU (was 384 = 1.5/CU)
  hipLaunchKernelGGL((gemm_bt<4, 64, float, bf16>), dim3(128, 6), blk, 0, stream, ctx, wob, bo, x, x1, 8192, 768, 768);
  hipLaunchKernelGGL((ln_kernel<bf16>), dim3(8192), blk, 0, stream, x1, h, alpha2, beta2);
  hipLaunchKernelGGL((gemm_bt<1, 128, float, bf16>), dim3(64, 24), blk, 0, stream, h, w1b, b1, (const float*)nullptr, ff, 8192, 3072, 768);
  hipLaunchKernelGGL((gemm_bt<4, 64, bf16, float>), dim3(128, 6), blk, 0, stream, ff, w2b, b2, x1, out, 8192, 768, 3072);
}